// Round 4
// baseline (347.992 us; speedup 1.0000x reference)
//
#include <hip/hip_runtime.h>

// conv2d NCHW fp32: X[32,64,112,112] * W[128,64,3,3], pad=1 -> out[32,128,112,112].
//
// v4: (a) conv_ring — block = (b, fg, 14-row strip); weights staged once per
// block (2x/CU vs 7x in v3); input rows in a 6-slot LDS ring, next window
// prefetched into REGISTERS during compute (T14 issue-early/write-late) so
// staging overlaps MFMA. K-loop mapping/swizzles identical to verified v3.
// (b) prep_input v2 — coalesced loads: 8 consecutive lanes read 256B
// contiguous of one c-row (was: 64 scattered lines per instruction); 8x8 shfl
// butterfly on stride-8 lane groups. Fallback conv_mfma kept.

typedef __attribute__((ext_vector_type(8))) __bf16 bf16x8;
typedef __attribute__((ext_vector_type(4))) float f32x4;
typedef __attribute__((ext_vector_type(4))) unsigned int u32x4;

#define XROW 7296   // shorts per Xt (b,hp) row: 114 wp * 64 c
#define WPROW 114   // wp rows per ring slot

__device__ __forceinline__ unsigned short f2bf(float f) {
    unsigned u = __builtin_bit_cast(unsigned, f);
    u += 0x7FFF + ((u >> 16) & 1);  // round-to-nearest-even
    return (unsigned short)(u >> 16);
}

__device__ __forceinline__ void gload_lds16(const unsigned short* g, unsigned short* l) {
    __builtin_amdgcn_global_load_lds(
        (const __attribute__((address_space(1))) unsigned int*)g,
        (__attribute__((address_space(3))) unsigned int*)l, 16, 0, 0);
}
__device__ __forceinline__ void gload_lds4(const unsigned short* g, unsigned short* l) {
    __builtin_amdgcn_global_load_lds(
        (const __attribute__((address_space(1))) unsigned int*)g,
        (__attribute__((address_space(3))) unsigned int*)l, 4, 0, 0);
}

// ---- prep: W[f][c][kh][kw] fp32 -> wsA[off][f][c] (plain, fallback) and
// wsS[off][f][slot] with slot s holding c-octet s^(f&7) (linear LDS copy of
// wsS yields conflict-free b128 A-reads) ----
__global__ void prep_weights(const float* __restrict__ flt,
                             unsigned short* __restrict__ wsA,
                             unsigned short* __restrict__ wsS) {
    int idx = blockIdx.x * 256 + threadIdx.x;
    if (idx >= 9 * 128 * 64) return;
    int off = idx >> 13;
    int f   = (idx >> 6) & 127;
    int c   = idx & 63;
    unsigned short v = f2bf(flt[(f * 64 + c) * 9 + off]);
    wsA[idx] = v;
    int cq = c >> 3, cl = c & 7;
    wsS[(off * 128 + f) * 64 + ((cq ^ (f & 7)) * 8 + cl)] = v;
}

// ---- prep: X[b][c][h][w] f32 -> Xt[b][hp][wp][c] bf16, zero-padded halo ----
// v2: wave = one c-octet; lane (cr=lane>>3, wq=lane&7) reads 32B of row
// c0+cr at w = wb + wq*8 .. +7 — 8 consecutive lanes cover 256B contiguous.
// Butterfly transposes within stride-8 lane groups (fixed wq, cr 0..7).
__global__ __launch_bounds__(512, 4)
void prep_input(const float* __restrict__ x, unsigned short* __restrict__ xt) {
    __shared__ __align__(16) unsigned short T[112 * 64];
    const int tid  = threadIdx.x;
    const int b    = blockIdx.x / 112;
    const int h    = blockIdx.x - b * 112;
    const int lane = tid & 63;
    const int wv   = tid >> 6;          // wave = c-octet index
    const int cr   = lane >> 3;         // c within octet
    const int wq   = lane & 7;          // w-octet within 64-w block
    const float* plane = x + (((size_t)b * 64 + wv * 8 + cr) * 112 + h) * 112;

    for (int it = 0; it < 2; ++it) {
        int wb = it * 64;               // it1 covers w 64..111 (wq<6)
        if (it == 0 || wq < 6) {
            const float* src = plane + wb + wq * 8;
            f32x4 f0 = *(const f32x4*)src;
            f32x4 f1 = *(const f32x4*)(src + 4);
            float r[8] = {f0.x, f0.y, f0.z, f0.w, f1.x, f1.y, f1.z, f1.w};
#pragma unroll
            for (int dd = 1; dd < 8; dd <<= 1) {
#pragma unroll
                for (int jA = 0; jA < 8; ++jA) {
                    if (jA & dd) continue;
                    int jB = jA | dd;
                    float give = (cr & dd) ? r[jA] : r[jB];
                    float got  = __shfl_xor(give, dd * 8, 64);
                    if (cr & dd) r[jA] = got; else r[jB] = got;
                }
            }
            // lane now holds c = wv*8 + j (reg j) for w = wb + wq*8 + cr
            int w = wb + wq * 8 + cr;
            unsigned pk[4];
#pragma unroll
            for (int j = 0; j < 4; ++j)
                pk[j] = (unsigned)f2bf(r[2 * j]) | ((unsigned)f2bf(r[2 * j + 1]) << 16);
            *(u32x4*)&T[w * 64 + ((wv ^ (w & 7)) * 8)] = u32x4{pk[0], pk[1], pk[2], pk[3]};
        }
    }
    __syncthreads();

    unsigned short* dst = xt + ((size_t)b * 114 + (h + 1)) * XROW;
    for (int ch = tid; ch < 912; ch += 512) {   // 114 wp * 8 chunks of 16B
        int wp = ch >> 3, cq = ch & 7;
        u32x4 v = {0, 0, 0, 0};
        if (wp >= 1 && wp <= 112) {
            int w = wp - 1;
            v = *(const u32x4*)&T[w * 64 + (cq ^ (w & 7)) * 8];
        }
        *(u32x4*)&dst[(size_t)ch * 8] = v;
    }
    if (h == 0 || h == 111) {
        unsigned short* zr = xt + ((size_t)b * 114 + (h == 0 ? 0 : 113)) * XROW;
        for (int ch = tid; ch < 912; ch += 512)
            *(u32x4*)&zr[(size_t)ch * 8] = u32x4{0, 0, 0, 0};
    }
}

// ---- all-LDS K-loop, ring-slot addressed: 64f x NTW w-tiles x 1 row ----
template <int TW0, int NTW>
__device__ __forceinline__ void kloop_ring(const unsigned short* Ws,
                                           const unsigned short* Bs,
                                           int rb0, int rb1, int rb2,
                                           float* obase, int l16, int q) {
    f32x4 acc[4][NTW];
#pragma unroll
    for (int mt = 0; mt < 4; ++mt)
#pragma unroll
        for (int t = 0; t < NTW; ++t) acc[mt][t] = {0.f, 0.f, 0.f, 0.f};

    const int rbs[3] = {rb0, rb1, rb2};
    const int e = l16 & 7;
#pragma unroll
    for (int off = 0; off < 9; ++off) {
        const int kh = off / 3;            // compile-time (unrolled)
        const int kw = off - kh * 3;
        const int rb = rbs[kh];
#pragma unroll
        for (int cs = 0; cs < 2; ++cs) {
            const int cq = cs * 4 + q;
            const int ca = cq ^ e;
            bf16x8 a0 = *(const bf16x8*)&Ws[(off * 64 +      l16) * 64 + ca * 8];
            bf16x8 a1 = *(const bf16x8*)&Ws[(off * 64 + 16 + l16) * 64 + ca * 8];
            bf16x8 a2 = *(const bf16x8*)&Ws[(off * 64 + 32 + l16) * 64 + ca * 8];
            bf16x8 a3 = *(const bf16x8*)&Ws[(off * 64 + 48 + l16) * 64 + ca * 8];
#pragma unroll
            for (int t = 0; t < NTW; ++t) {
                int wp = (TW0 + t) * 16 + l16 + kw;
                int cb = cq ^ (wp & 7);
                bf16x8 bv = *(const bf16x8*)&Bs[rb + wp * 64 + cb * 8];
                acc[0][t] = __builtin_amdgcn_mfma_f32_16x16x32_bf16(a0, bv, acc[0][t], 0, 0, 0);
                acc[1][t] = __builtin_amdgcn_mfma_f32_16x16x32_bf16(a1, bv, acc[1][t], 0, 0, 0);
                acc[2][t] = __builtin_amdgcn_mfma_f32_16x16x32_bf16(a2, bv, acc[2][t], 0, 0, 0);
                acc[3][t] = __builtin_amdgcn_mfma_f32_16x16x32_bf16(a3, bv, acc[3][t], 0, 0, 0);
            }
        }
    }
#pragma unroll
    for (int mt = 0; mt < 4; ++mt)
#pragma unroll
        for (int t = 0; t < NTW; ++t) {
            float* o = obase + (size_t)(mt * 16) * 12544 + (TW0 + t) * 16 + l16;
#pragma unroll
            for (int r2 = 0; r2 < 4; ++r2)
                o[(size_t)r2 * 12544] = acc[mt][t][r2];
        }
}

__global__ __launch_bounds__(512, 2)
void conv_ring(const unsigned short* __restrict__ xt,
               const unsigned short* __restrict__ wsS,
               float* __restrict__ out) {
    __shared__ __align__(16) unsigned short Ws[9 * 64 * 64];      // 73728 B
    __shared__ __align__(16) unsigned short Bs[6 * WPROW * 64];   // 87552 B

    const int tid = threadIdx.x;
    const int id  = blockIdx.x;            // 512 = 32 b x 2 fg x 8 strips
    const int xcd = id & 7;
    const int u   = id >> 3;               // [0,64)
    const int lin = xcd * 64 + u;          // contiguous chunk per XCD
    const int b     = lin >> 4;            // [0,32)
    const int fg    = (lin >> 3) & 1;      // 64-filter group
    const int strip = lin & 7;             // [0,8)
    const int H0    = strip * 14;          // output rows H0..H0+13

    const int lane = tid & 63;
    const int wid  = tid >> 6;

    const unsigned short* xb = xt + (size_t)b * 114 * XROW;

    // ---- initial stage: Ws (72 segs) + Xt rows H0..H0+5 into ring slots ----
    {
        const int l3 = lane >> 3, j = lane & 7;
        for (int i = wid; i < 156; i += 8) {
            if (i < 72) {
                int off = i >> 3, k = i & 7;
                gload_lds16(wsS + off * 8192 + fg * 4096 + k * 512 + lane * 8,
                            &Ws[off * 4096 + k * 512]);
            } else {
                int i2 = i - 72;
                int rp = i2 / 14, seg = i2 - rp * 14;
                int slot = (H0 + rp) % 6;
                int wp = seg * 8 + l3;                 // <= 111
                gload_lds16(xb + (size_t)(H0 + rp) * XROW + wp * 64 + ((j ^ (wp & 7)) * 8),
                            &Bs[(slot * WPROW + seg * 8) * 64]);
            }
        }
        if (wid < 6) {   // tails wp=112,113 per row: 256B width-4 copy
            int rp = wid;
            int slot = (H0 + rp) % 6;
            int wp = 112 + (lane >> 5);
            int cq = (lane & 31) >> 2;
            gload_lds4(xb + (size_t)(H0 + rp) * XROW + wp * 64 + (cq ^ (wp & 7)) * 8 + (lane & 3) * 2,
                       &Bs[(slot * WPROW + 112) * 64]);
        }
    }
    __syncthreads();

    const int l16 = lane & 15;
    const int q   = lane >> 4;
    const int rr  = wid & 3;               // output row within step
    const int wsp = wid >> 2;              // w-split

    for (int s = 0; s < 4; ++s) {
        const int nrows = (s < 3) ? 4 : 2; // steps: 4,4,4,2 rows
        const int hs = H0 + 4 * s;

        // ---- T14 issue-early: load next-window rows into registers ----
        u32x4 st0[4], st1[4];
        const int nnext = (s < 2) ? 4 : (s == 2 ? 2 : 0);
        const int hnext = hs + 6;
#pragma unroll
        for (int r = 0; r < 4; ++r) {
            if (r < nnext) {
                const unsigned short* src = xb + (size_t)(hnext + r) * XROW;
                st0[r] = *(const u32x4*)(src + tid * 8);
                if (tid < 400) st1[r] = *(const u32x4*)(src + (size_t)(512 + tid) * 8);
            }
        }

        // ---- compute nrows output rows from ring window [hs, hs+5] ----
        if (rr < nrows) {
            const int h = hs + rr;
            int rb[3];
#pragma unroll
            for (int kh = 0; kh < 3; ++kh) {
                int t = (hs % 6) + rr + kh;      // <= 10
                if (t >= 6) t -= 6;
                rb[kh] = t * (WPROW * 64);
            }
            float* obase = out + (((size_t)b * 128 + fg * 64 + q * 4) * 112 + h) * 112;
            if (wsp == 0) kloop_ring<0, 4>(Ws, Bs, rb[0], rb[1], rb[2], obase, l16, q);
            else          kloop_ring<4, 3>(Ws, Bs, rb[0], rb[1], rb[2], obase, l16, q);
        }
        __syncthreads();   // waves done reading dying slots; prefetch arrived

        // ---- T14 write-late: ds_write prefetched rows into freed slots ----
        if (s < 3) {
#pragma unroll
            for (int r = 0; r < 4; ++r) {
                if (r < nnext) {
                    int slot = (hnext + r) % 6;
                    int wp = tid >> 3, cq = tid & 7;
                    *(u32x4*)&Bs[(slot * WPROW + wp) * 64 + ((cq ^ (wp & 7)) * 8)] = st0[r];
                    if (tid < 400) {
                        int ch2 = 512 + tid;
                        int wp2 = ch2 >> 3, cq2 = ch2 & 7;
                        *(u32x4*)&Bs[(slot * WPROW + wp2) * 64 + ((cq2 ^ (wp2 & 7)) * 8)] = st1[r];
                    }
                }
            }
            __syncthreads();
        }
    }
}

// ======================= fallback (old kernel, unchanged) ====================
#define ROWS_PER_KH 124
#define ROW_SHORTS 64

__global__ __launch_bounds__(512, 4)
void conv_mfma(const float* __restrict__ x,
               const unsigned short* __restrict__ wsA,
               float* __restrict__ out) {
    __shared__ __align__(16) unsigned short Bso[4 * ROWS_PER_KH * ROW_SHORTS];

    const int tid = threadIdx.x;
    const int id  = blockIdx.x;
    const int xcd = id & 7;
    const int s   = id >> 3;
    const int b   = s / 7;
    const int hpl = s - b * 7;
    const int hp  = xcd * 7 + hpl;
    const int h0  = hp * 2;

    if (tid < 32) {
        int kh = tid >> 3, cq = tid & 7;
        int R = kh * ROWS_PER_KH;
        int chunk = cq ^ (R & 7);
        *(u32x4*)&Bso[R * ROW_SHORTS + chunk * 8] = u32x4{0, 0, 0, 0};
    }

    const int li   = tid & 7;
    const int unit = tid >> 3;
    for (int it = 0; it < 8; ++it) {
        int u = it * 64 + unit;
        if (u < 480) {
            int wo = u >> 5;
            int rc = u & 31;
            int rp = rc >> 3;
            int cq = rc & 7;
            int hr = h0 + rp - 1;
            int c  = cq * 8 + li;
            f32x4 f0 = {0.f, 0.f, 0.f, 0.f}, f1 = {0.f, 0.f, 0.f, 0.f};
            if ((unsigned)hr < 112u && wo < 14) {
                const float* src = x + (((size_t)b * 64 + c) * 112 + hr) * 112 + wo * 8;
                f0 = *(const f32x4*)src;
                f1 = *(const f32x4*)(src + 4);
            }
            float r[8] = {f0.x, f0.y, f0.z, f0.w, f1.x, f1.y, f1.z, f1.w};
#pragma unroll
            for (int d = 1; d < 8; d <<= 1) {
#pragma unroll
                for (int jA = 0; jA < 8; ++jA) {
                    if (jA & d) continue;
                    int jB = jA | d;
                    float give = (li & d) ? r[jA] : r[jB];
                    float got  = __shfl_xor(give, d, 64);
                    if (li & d) r[jA] = got; else r[jB] = got;
                }
            }
            int R = rp * ROWS_PER_KH + wo * 8 + li + 1;
            int chunk = cq ^ (R & 7);
            unsigned pk[4];
#pragma unroll
            for (int j = 0; j < 4; ++j)
                pk[j] = (unsigned)f2bf(r[2 * j]) | ((unsigned)f2bf(r[2 * j + 1]) << 16);
            *(u32x4*)&Bso[R * ROW_SHORTS + chunk * 8] = u32x4{pk[0], pk[1], pk[2], pk[3]};
        }
    }
    __syncthreads();

    const int lane = tid & 63;
    const int wid  = tid >> 6;
    const int fg   = wid & 3;
    const int rr   = wid >> 2;
    const int q    = lane >> 4;
    const int l16  = lane & 15;
    const int h    = h0 + rr;

    f32x4 acc[2][7];
#pragma unroll
    for (int mt = 0; mt < 2; ++mt)
#pragma unroll
        for (int tw = 0; tw < 7; ++tw)
            acc[mt][tw] = {0.f, 0.f, 0.f, 0.f};

    const unsigned short* wA = wsA + (fg * 32 + l16) * 64 + q * 8;

#pragma unroll
    for (int off = 0; off < 9; ++off) {
        const int kh = off / 3;
        const int kw = off - kh * 3;
        const int Rbase = (rr + kh) * ROWS_PER_KH + kw;
#pragma unroll
        for (int cs = 0; cs < 2; ++cs) {
            bf16x8 a0 = *(const bf16x8*)(wA + off * 8192 + cs * 32);
            bf16x8 a1 = *(const bf16x8*)(wA + off * 8192 + 1024 + cs * 32);
            const int cq = cs * 4 + q;
#pragma unroll
            for (int tw = 0; tw < 7; ++tw) {
                int R = Rbase + tw * 16 + l16;
                int chunk = cq ^ (R & 7);
                bf16x8 bv = *(const bf16x8*)&Bso[R * ROW_SHORTS + chunk * 8];
                acc[0][tw] = __builtin_amdgcn_mfma_f32_16x16x32_bf16(a0, bv, acc[0][tw], 0, 0, 0);
                acc[1][tw] = __builtin_amdgcn_mfma_f32_16x16x32_bf16(a1, bv, acc[1][tw], 0, 0, 0);
            }
        }
    }

#pragma unroll
    for (int mt = 0; mt < 2; ++mt) {
#pragma unroll
        for (int tw = 0; tw < 7; ++tw) {
            int f = fg * 32 + mt * 16 + q * 4;
            int w = tw * 16 + l16;
            float* o = out + (((size_t)b * 128 + f) * 112 + h) * 112 + w;
#pragma unroll
            for (int r2 = 0; r2 < 4; ++r2)
                o[(size_t)r2 * 12544] = acc[mt][tw][r2];
        }
    }
}

extern "C" void kernel_launch(void* const* d_in, const int* in_sizes, int n_in,
                              void* d_out, int out_size, void* d_ws, size_t ws_size,
                              hipStream_t stream) {
    const float* x   = (const float*)d_in[0];   // dataset [32,64,112,112]
    const float* flt = (const float*)d_in[1];   // filters [128,64,3,3]
    float* out = (float*)d_out;
    unsigned short* wsA = (unsigned short*)d_ws;       // plain weights (fallback)
    unsigned short* wsS = wsA + 73728;                 // swizzled weights
    unsigned short* xxt = wsA + 147456;                // Xt [32][114][114][64]

    hipLaunchKernelGGL(prep_weights, dim3(288), dim3(256), 0, stream, flt, wsA, wsS);

    const size_t XT_SHORTS = (size_t)32 * 114 * 114 * 64;      // 26,615,808
    const size_t need = (147456 + XT_SHORTS) * 2;              // 53,526,528 B
    if (ws_size >= need) {
        hipLaunchKernelGGL(prep_input, dim3(3584), dim3(512), 0, stream, x, xxt);
        hipLaunchKernelGGL(conv_ring, dim3(512), dim3(512), 0, stream, xxt, wsS, out);
    } else {
        hipLaunchKernelGGL(conv_mfma, dim3(1792), dim3(512), 0, stream, x, wsA, out);
    }
}